// Round 14
// baseline (419.033 us; speedup 1.0000x reference)
//
#include <hip/hip_runtime.h>
#include <cmath>
#include <stdint.h>

#define NPTS   86016
#define NB     (1 << 18)     // fine histogram bins per level (f32 score bits >> 12)
#define NCB    1024          // coarse bins per level (bits >> 20); coarse = fine >> 8
#define K_TOP  1000
#define NOUT   3000
#define NWORDS 47            // ceil(3000/64)
#define NTILE  47
#define CAND_CAP 16384
#define ECAP   8192          // edge capacity (expected E ~ hundreds)
#define FCAP   1024          // tie-flag capacity (expected ~20)
#define SPPB   64            // score points per block (1344 blocks)

// ---- workspace layout (bytes): fine hist, coarse hist, cnt contiguous (one memset) ----
#define HIST_OFF   0
#define CH_OFF     (NB * 3 * 4)                 // 3,145,728
#define CNT_OFF    (CH_OFF + NCB * 3 * 4)       // +12,288
// cnt[0..2]=sure_cnt [3..5]=cand_cnt [6..8]=binB [9..11]=Rneed [12]=edge_cnt [13]=flag_cnt
#define MEMSET_BYTES (CNT_OFF + 64)
#define KEYS_OFF   (CNT_OFF + 64)
#define LAB_OFF    (KEYS_OFF + NPTS * 8)
#define SURE_OFF   (LAB_OFF + NPTS * 4)
#define CAND_OFF   (SURE_OFF + 3 * 1024 * 8)
#define SURV_OFF   (CAND_OFF + 3 * CAND_CAP * 8)
#define EDGE_OFF   (SURV_OFF + NOUT * 8 + 64)
#define FLAG_OFF   (EDGE_OFF + ECAP * 4)

// stepwise-f32 sigmoid: CR f32 exp, then IEEE f32 add + div (matches numpy per-op chain)
__device__ __forceinline__ float sig_f32_stepwise(float x) {
    float e = (float)exp(-(double)x);   // correctly-rounded f32 exp(-x)
    return 1.0f / (1.0f + e);           // f32 add (CR), f32 div (CR)
}

__device__ __forceinline__ void locate(int g, int& lv, int& p, int& HW) {
    if (g < 65536)      { lv = 0; p = g;         HW = 65536; }
    else if (g < 81920) { lv = 1; p = g - 65536; HW = 16384; }
    else                { lv = 2; p = g - 81920; HW = 4096;  }
}

// ---------------- kernel 1: fused score (chunked max scan in LDS + combine) ----------------
__global__ __launch_bounds__(256) void score_kernel(
        const float* __restrict__ cls0, const float* __restrict__ cls1,
        const float* __restrict__ cls2,
        const float* __restrict__ ctn0, const float* __restrict__ ctn1,
        const float* __restrict__ ctn2,
        unsigned long long* __restrict__ keys, int* __restrict__ labels,
        int* __restrict__ hist, int* __restrict__ chist,
        int* __restrict__ cnt, unsigned* __restrict__ flags) {
    __shared__ float pm[5 * SPPB], pv[5 * SPPB];
    __shared__ int pidx[5 * SPPB];
    const int tid = threadIdx.x;
    const int base = blockIdx.x * SPPB;
    for (int it = tid; it < 5 * SPPB; it += 256) {
        int c = it / SPPB, pt = it - c * SPPB;
        int g = base + pt, lv, p, HW;
        locate(g, lv, p, HW);
        const float* cls = (lv == 0) ? cls0 : ((lv == 1) ? cls1 : cls2);
        const float* bp = cls + (size_t)c * 16 * HW + p;
        float x[16];
#pragma unroll
        for (int cc = 0; cc < 16; cc++) x[cc] = bp[(size_t)cc * HW];   // independent loads (MLP)
        float m = -INFINITY, v = -INFINITY; int idx = 0;
#pragma unroll
        for (int cc = 0; cc < 16; cc++)
            if (x[cc] > m) { v = m; m = x[cc]; idx = c * 16 + cc; }    // first-occurrence
        pm[it] = m; pv[it] = v; pidx[it] = idx;
    }
    __syncthreads();
    if (tid < SPPB) {
        int g = base + tid, lv, p, HW;
        locate(g, lv, p, HW);
        const float* ctn = (lv == 0) ? ctn0 : ((lv == 1) ? ctn1 : ctn2);
        float m = -INFINITY, v = -INFINITY; int idx = 0;
#pragma unroll
        for (int k = 0; k < 5; k++) {
            float bm = pm[k * SPPB + tid];
            float bv = pv[k * SPPB + tid];
            int bidx = pidx[k * SPPB + tid];
            if (bm > m) { v = fmaxf(m, bv); m = bm; idx = bidx; }
        }
        // joint = sqrt(sig(cls)*sig(ctn)) weakly monotone in cls -> max joint = joint(m)
        float sc = sig_f32_stepwise(ctn[p]);
        float sM = sig_f32_stepwise(m);
        float jm = __fsqrt_rn(sM * sc);
        float sV = sig_f32_stepwise(v);
        float jv = __fsqrt_rn(sV * sc);
        if (jv == jm) {                        // earlier-index label tie possible
            int f = atomicAdd(&cnt[13], 1);
            if (f < FCAP) flags[f] = (unsigned)g;
        }
        unsigned int bits = __float_as_uint(jm);
        keys[g] = ((unsigned long long)bits << 32) | (0xFFFFFFFFu - (unsigned)g);
        labels[g] = idx;
        atomicAdd(&hist[lv * NB + (int)(bits >> 12)], 1);     // fine
        atomicAdd(&chist[lv * NCB + (int)(bits >> 20)], 1);   // coarse (= fine >> 8)
    }
}

// ---------------- kernel 2: thresh via coarse+fine hist (blocks 0-2) + cleanup (block 3) ----
__global__ __launch_bounds__(1024) void thresh_kernel(
        const float* __restrict__ cls0, const float* __restrict__ cls1,
        const float* __restrict__ cls2,
        const float* __restrict__ ctn0, const float* __restrict__ ctn1,
        const float* __restrict__ ctn2,
        const int* __restrict__ hist, const int* __restrict__ chist,
        int* __restrict__ cnt,
        const unsigned* __restrict__ flags, int* __restrict__ labels) {
    int bid = blockIdx.x, tid = threadIdx.x;
    if (bid < 3) {
        int lv = bid;
        const int* h = hist + lv * NB;
        __shared__ int part[1024];
        __shared__ int s_chunk, s_above;
        __shared__ int bins[257];
        part[tid] = chist[lv * NCB + tid];     // coarse bin count == sum of its 256 fine bins
        __syncthreads();
        for (int off = 1; off < 1024; off <<= 1) {
            int v = part[tid] + ((tid + off < 1024) ? part[tid + off] : 0);
            __syncthreads(); part[tid] = v; __syncthreads();
        }
        int nxt = (tid < 1023) ? part[tid + 1] : 0;
        if (part[tid] >= K_TOP && nxt < K_TOP) { s_chunk = tid; s_above = nxt; }
        __syncthreads();
        int chunk = s_chunk, above = s_above;
        if (tid < 256) bins[tid] = h[chunk * 256 + tid];
        __syncthreads();
        for (int off = 1; off < 256; off <<= 1) {
            int v = 0;
            if (tid < 256) v = bins[tid] + ((tid + off < 256) ? bins[tid + off] : 0);
            __syncthreads(); if (tid < 256) bins[tid] = v; __syncthreads();
        }
        if (tid < 256) {
            int ge    = above + bins[tid];
            int genxt = above + ((tid < 255) ? bins[tid + 1] : 0);
            if (ge >= K_TOP && genxt < K_TOP) {
                cnt[6 + lv] = chunk * 256 + tid;  // cutoff bin B (fine)
                cnt[9 + lv] = K_TOP - genxt;      // R needed from bin B
            }
        }
    } else {
        // cleanup: one wave per flagged point, shuffle argmax-reduce (first occurrence = min idx)
        int nf = cnt[13]; if (nf > FCAP) nf = FCAP;
        int wave = tid >> 6, lane = tid & 63;
        for (int f = wave; f < nf; f += 16) {
            int g = (int)flags[f], lv, p, HW;
            locate(g, lv, p, HW);
            const float* cls = (lv == 0) ? cls0 : ((lv == 1) ? cls1 : cls2);
            const float* ctn = (lv == 0) ? ctn0 : ((lv == 1) ? ctn1 : ctn2);
            float sc = sig_f32_stepwise(ctn[p]);
            float bestv = -1.0f; int besti = 127;
            {
                float s = sig_f32_stepwise(cls[(size_t)lane * HW + p]);
                float sj = __fsqrt_rn(s * sc);
                bestv = sj; besti = lane;
            }
            if (lane < 16) {
                int c2 = lane + 64;
                float s = sig_f32_stepwise(cls[(size_t)c2 * HW + p]);
                float sj = __fsqrt_rn(s * sc);
                if (sj > bestv) { bestv = sj; besti = c2; }   // tie keeps smaller idx
            }
            for (int off = 32; off; off >>= 1) {
                float ov = __shfl_xor(bestv, off, 64);
                int   oi = __shfl_xor(besti, off, 64);
                if (ov > bestv || (ov == bestv && oi < besti)) { bestv = ov; besti = oi; }
            }
            if (lane == 0) labels[g] = besti;
        }
    }
}

// ---------------- kernel 3: compact sure / candidate keys ----------------
__global__ void compact_kernel(const unsigned long long* __restrict__ keys,
                               int* __restrict__ cnt,
                               unsigned long long* __restrict__ sure,
                               unsigned long long* __restrict__ cand) {
    int g = blockIdx.x * blockDim.x + threadIdx.x;
    if (g >= NPTS) return;
    int lv = (g < 65536) ? 0 : (g < 81920 ? 1 : 2);
    unsigned long long key = keys[g];
    int bin = (int)(key >> 44);      // == f32 bits >> 12
    int B = cnt[6 + lv];
    if (bin > B) {
        int i = atomicAdd(&cnt[0 + lv], 1);
        sure[lv * 1024 + i] = key;
    } else if (bin == B) {
        int i = atomicAdd(&cnt[3 + lv], 1);
        if (i < CAND_CAP) cand[lv * CAND_CAP + i] = key;
    }
}

// ---------------- kernel 4: per-level candidate sort + fully-sorted level list ----------------
__global__ void select_kernel(const int* __restrict__ cnt,
                              const unsigned long long* __restrict__ sure,
                              unsigned long long* __restrict__ cand,
                              unsigned long long* __restrict__ surv) {
    int lv = blockIdx.x, tid = threadIdx.x;
    unsigned long long* c = cand + lv * CAND_CAP;
    int n = cnt[3 + lv]; if (n > CAND_CAP) n = CAND_CAP;
    int R = cnt[9 + lv];
    int Ca = K_TOP - R;
    int m = 1; while (m < n) m <<= 1;
    for (int t = n + tid; t < m; t += 1024) c[t] = 0ULL;
    __syncthreads();
    for (int k = 2; k <= m; k <<= 1)
        for (int j = k >> 1; j > 0; j >>= 1) {
            for (int t = tid; t < m; t += 1024) {
                int l = t ^ j;
                if (l > t) {
                    unsigned long long a = c[t], b = c[l];
                    if (((t & k) == 0) ? (a < b) : (a > b)) { c[t] = b; c[l] = a; }
                }
            }
            __syncthreads();
        }
    __shared__ unsigned long long s[1024];
    s[tid] = (tid < Ca) ? sure[lv * 1024 + tid]
                        : ((tid < K_TOP) ? c[tid - Ca] : 0ULL);
    __syncthreads();
    for (int k = 2; k <= 1024; k <<= 1)
        for (int j = k >> 1; j > 0; j >>= 1) {
            int l = tid ^ j;
            if (l > tid) {
                unsigned long long a = s[tid], b = s[l];
                if (((tid & k) == 0) ? (a < b) : (a > b)) { s[tid] = b; s[l] = a; }
            }
            __syncthreads();
        }
    if (tid < K_TOP) surv[lv * K_TOP + tid] = s[tid];    // sorted descending
}

// ---------------- kernel 5: 3-way merge by ranking + emit ----------------
__global__ __launch_bounds__(1024) void merge_emit_kernel(
        const unsigned long long* __restrict__ surv,
        const int* __restrict__ labels,
        const float* __restrict__ reg0, const float* __restrict__ reg1,
        const float* __restrict__ reg2,
        const float* __restrict__ scales,
        float* __restrict__ out) {
    __shared__ unsigned long long L[3][1024];
    __shared__ unsigned long long s[NOUT];
    int tid = threadIdx.x;
#pragma unroll
    for (int lv = 0; lv < 3; lv++)
        L[lv][tid] = (tid < K_TOP) ? surv[lv * K_TOP + tid] : 0ULL;
    __syncthreads();
    for (int e = tid; e < NOUT; e += 1024) {
        int a = e / K_TOP, i = e - a * K_TOP;
        unsigned long long key = L[a][i];
        int rank = i;
#pragma unroll
        for (int b = 0; b < 3; b++) {
            if (b == a) continue;
            int lo = 0, hi = K_TOP;
            while (lo < hi) {
                int mid = (lo + hi) >> 1;
                if (L[b][mid] > key) lo = mid + 1; else hi = mid;
            }
            rank += lo;
        }
        s[rank] = key;    // keys unique -> bijective
    }
    __syncthreads();
    for (int r = tid; r < NOUT; r += 1024) {
        unsigned long long key = s[r];
        unsigned int bits = (unsigned)(key >> 32);
        float score = __uint_as_float(bits);
        unsigned int g = 0xFFFFFFFFu - (unsigned)(key & 0xFFFFFFFFULL);
        int lv, p;
        if (g < 65536u)      { lv = 0; p = (int)g; }
        else if (g < 81920u) { lv = 1; p = (int)g - 65536; }
        else                 { lv = 2; p = (int)g - 81920; }
        const float* rp = (lv == 0) ? reg0 : ((lv == 1) ? reg1 : reg2);
        int HW = (lv == 0) ? 65536 : ((lv == 1) ? 16384 : 4096);
        int W = 256 >> lv;
        float strideF = (float)(8 << lv);
        float scale = scales[lv];
        int x = p & (W - 1);
        int y = p >> (8 - lv);
        float r0 = fmaxf(0.0f, rp[0 * HW + p] * scale) * strideF;
        float r1 = fmaxf(0.0f, rp[1 * HW + p] * scale) * strideF;
        float r2 = fmaxf(0.0f, rp[2 * HW + p] * scale) * strideF;
        float r3 = fmaxf(0.0f, rp[3 * HW + p] * scale) * strideF;
        float ax = ((float)x + 0.5f) * strideF;
        float ay = ((float)y + 0.5f) * strideF;
        out[r * 4 + 0] = ax - r0;
        out[r * 4 + 1] = ay - r1;
        out[r * 4 + 2] = ax + r2;
        out[r * 4 + 3] = ay + r3;
        out[12000 + r] = score;
        out[15000 + r] = (float)labels[g];
    }
}

// ---------------- kernel 6: tiled sparse edge extraction (SoA LDS) ----------------
__global__ __launch_bounds__(256) void edge_kernel(const float* __restrict__ out,
                                                   unsigned* __restrict__ edges_g,
                                                   int* __restrict__ cnt) {
    __shared__ float x1[128], y1[128], x2[128], y2[128];
    int t = blockIdx.x, tid = threadIdx.x;
    int ta = 0, rem = t;
    while (rem >= NTILE - ta) { rem -= NTILE - ta; ta++; }
    int tb = ta + rem;                         // ta <= tb
    if (tid < 64) {
        int gi = ta * 64 + tid;
        if (gi < NOUT) {
            float4 b = ((const float4*)out)[gi];
            x1[tid] = b.x; y1[tid] = b.y; x2[tid] = b.z; y2[tid] = b.w;
        }
    } else if (tid < 128) {
        int gj = tb * 64 + (tid - 64);
        if (gj < NOUT) {
            float4 b = ((const float4*)out)[gj];
            x1[tid] = b.x; y1[tid] = b.y; x2[tid] = b.z; y2[tid] = b.w;
        }
    }
    __syncthreads();
#pragma unroll
    for (int q = 0; q < 16; q++) {
        int idx = q * 256 + tid;
        int ii = idx >> 6, jj = idx & 63;
        int i = ta * 64 + ii, j = tb * 64 + jj;
        if (i < j && j < NOUT) {
            float ai = (x2[ii] - x1[ii]) * (y2[ii] - y1[ii]);
            float aj = (x2[64 + jj] - x1[64 + jj]) * (y2[64 + jj] - y1[64 + jj]);
            float xx1 = fmaxf(x1[ii], x1[64 + jj]), yy1 = fmaxf(y1[ii], y1[64 + jj]);
            float xx2 = fminf(x2[ii], x2[64 + jj]), yy2 = fminf(y2[ii], y2[64 + jj]);
            float ww = fmaxf(1e-10f, xx2 - xx1);
            float hh = fmaxf(1e-10f, yy2 - yy1);
            float inter = ww * hh;
            float iou = inter / (((ai + aj) - inter) + 1e-14f);
            if ((double)iou > 0.6) {
                int e = atomicAdd(&cnt[12], 1);
                if (e < ECAP) edges_g[e] = ((unsigned)i << 12) | (unsigned)j;
            }
        }
    }
}

// ---------------- kernel 7: sparse sequential NMS (single block) ----------------
__global__ __launch_bounds__(1024) void nms_sparse_kernel(
        const unsigned* __restrict__ edges_g,
        const int* __restrict__ cnt,
        const float* __restrict__ scores_s,
        float* __restrict__ keep_out) {
    __shared__ unsigned ed[ECAP];
    __shared__ unsigned long long supLds[NWORDS];
    int tid = threadIdx.x;
    int E = cnt[12]; if (E > ECAP) E = ECAP;
    int m = 1; while (m < E) m <<= 1;
    for (int t = tid; t < m; t += 1024) ed[t] = (t < E) ? edges_g[t] : 0xFFFFFFFFu;
    __syncthreads();
    for (int k = 2; k <= m; k <<= 1)
        for (int j = k >> 1; j > 0; j >>= 1) {
            for (int t = tid; t < m; t += 1024) {
                int l = t ^ j;
                if (l > t) {
                    unsigned a = ed[t], b = ed[l];
                    if (((t & k) == 0) ? (a > b) : (a < b)) { ed[t] = b; ed[l] = a; }
                }
            }
            __syncthreads();
        }
    if (tid < 64) {
        int lane = tid;
        unsigned long long supW = 0ULL;
        int ep = 0;
        for (int c = 0; c < NWORDS; c++) {
            unsigned long long cw = __shfl(supW, c, 64);   // complete: sources < c*64 final
            int hi = (c + 1) * 64;
            while (ep < E) {
                unsigned k = ed[ep];
                int i = (int)(k >> 12);
                if (i >= hi) break;
                int j = (int)(k & 4095);
                if (!((cw >> (i & 63)) & 1ULL)) {          // source kept -> suppress target
                    if ((j >> 6) == c) cw |= 1ULL << (j & 63);
                    else if (lane == (j >> 6)) supW |= 1ULL << (j & 63);
                }
                ep++;
            }
            if (lane == c) supW = cw;
        }
        if (lane < NWORDS) supLds[lane] = supW;
    }
    __syncthreads();
    for (int j = tid; j < NOUT; j += 1024) {
        bool s = (supLds[j >> 6] >> (j & 63)) & 1ULL;
        float scv = scores_s[j];
        keep_out[j] = (!s && ((double)scv > 0.05)) ? 1.0f : 0.0f;
    }
}

extern "C" void kernel_launch(void* const* d_in, const int* in_sizes, int n_in,
                              void* d_out, int out_size, void* d_ws, size_t ws_size,
                              hipStream_t stream) {
    const float* cls0 = (const float*)d_in[0];
    const float* reg0 = (const float*)d_in[1];
    const float* ctn0 = (const float*)d_in[2];
    const float* cls1 = (const float*)d_in[3];
    const float* reg1 = (const float*)d_in[4];
    const float* ctn1 = (const float*)d_in[5];
    const float* cls2 = (const float*)d_in[6];
    const float* reg2 = (const float*)d_in[7];
    const float* ctn2 = (const float*)d_in[8];
    const float* scales = (const float*)d_in[9];

    char* ws = (char*)d_ws;
    int* hist = (int*)(ws + HIST_OFF);
    int* chist = (int*)(ws + CH_OFF);
    int* cnt  = (int*)(ws + CNT_OFF);
    unsigned long long* keys = (unsigned long long*)(ws + KEYS_OFF);
    int* labels = (int*)(ws + LAB_OFF);
    unsigned long long* sure = (unsigned long long*)(ws + SURE_OFF);
    unsigned long long* cand = (unsigned long long*)(ws + CAND_OFF);
    unsigned long long* surv = (unsigned long long*)(ws + SURV_OFF);
    unsigned* edges = (unsigned*)(ws + EDGE_OFF);
    unsigned* flags = (unsigned*)(ws + FLAG_OFF);
    float* out = (float*)d_out;

    hipMemsetAsync(ws, 0, MEMSET_BYTES, stream);

    score_kernel<<<NPTS / SPPB, 256, 0, stream>>>(cls0, cls1, cls2, ctn0, ctn1, ctn2,
                                                  keys, labels, hist, chist, cnt, flags);
    thresh_kernel<<<4, 1024, 0, stream>>>(cls0, cls1, cls2, ctn0, ctn1, ctn2,
                                          hist, chist, cnt, flags, labels);
    compact_kernel<<<(NPTS + 255) / 256, 256, 0, stream>>>(keys, cnt, sure, cand);
    select_kernel<<<3, 1024, 0, stream>>>(cnt, sure, cand, surv);
    merge_emit_kernel<<<1, 1024, 0, stream>>>(surv, labels, reg0, reg1, reg2, scales, out);
    edge_kernel<<<NTILE * (NTILE + 1) / 2, 256, 0, stream>>>(out, edges, cnt);
    nms_sparse_kernel<<<1, 1024, 0, stream>>>(edges, cnt, out + 12000, out + 18000);
}

// Round 15
// 193.392 us; speedup vs baseline: 2.1668x; 2.1668x over previous
//
#include <hip/hip_runtime.h>
#include <cmath>
#include <stdint.h>

#define NPTS   86016
#define NB     (1 << 18)     // fine histogram bins per level (f32 score bits >> 12)
#define NCB    1024          // coarse bins per level (bits >> 20); coarse = fine >> 8
#define K_TOP  1000
#define NOUT   3000
#define NWORDS 47            // ceil(3000/64)
#define NTILE  47
#define CAND_CAP 16384
#define ECAP   8192          // edge capacity (expected E ~ hundreds)
#define FCAP   1024          // tie-flag capacity (expected ~20)
#define SPPB   64            // score points per block (1344 blocks; 64 divides 65536 & 81920)

// ---- workspace layout (bytes): fine hist, coarse hist, cnt contiguous (one memset) ----
#define HIST_OFF   0
#define CH_OFF     (NB * 3 * 4)                 // 3,145,728
#define CNT_OFF    (CH_OFF + NCB * 3 * 4)       // +12,288
// cnt[0..2]=sure_cnt [3..5]=cand_cnt [6..8]=binB [9..11]=Rneed [12]=edge_cnt [13]=flag_cnt
#define MEMSET_BYTES (CNT_OFF + 64)
#define KEYS_OFF   (CNT_OFF + 64)
#define LAB_OFF    (KEYS_OFF + NPTS * 8)
#define SURE_OFF   (LAB_OFF + NPTS * 4)
#define CAND_OFF   (SURE_OFF + 3 * 1024 * 8)
#define SURV_OFF   (CAND_OFF + 3 * CAND_CAP * 8)
#define EDGE_OFF   (SURV_OFF + NOUT * 8 + 64)
#define FLAG_OFF   (EDGE_OFF + ECAP * 4)

// stepwise-f32 sigmoid: CR f32 exp, then IEEE f32 add + div (matches numpy per-op chain)
__device__ __forceinline__ float sig_f32_stepwise(float x) {
    float e = (float)exp(-(double)x);   // correctly-rounded f32 exp(-x)
    return 1.0f / (1.0f + e);           // f32 add (CR), f32 div (CR)
}

__device__ __forceinline__ void locate(int g, int& lv, int& p, int& HW) {
    if (g < 65536)      { lv = 0; p = g;         HW = 65536; }
    else if (g < 81920) { lv = 1; p = g - 65536; HW = 16384; }
    else                { lv = 2; p = g - 81920; HW = 4096;  }
}

// ---------------- kernel 1: fused score (chunked max scan + LDS-aggregated coarse hist) ----
__global__ __launch_bounds__(256) void score_kernel(
        const float* __restrict__ cls0, const float* __restrict__ cls1,
        const float* __restrict__ cls2,
        const float* __restrict__ ctn0, const float* __restrict__ ctn1,
        const float* __restrict__ ctn2,
        unsigned long long* __restrict__ keys, int* __restrict__ labels,
        int* __restrict__ hist, int* __restrict__ chist,
        int* __restrict__ cnt, unsigned* __restrict__ flags) {
    __shared__ float pm[5 * SPPB], pv[5 * SPPB];
    __shared__ int pidx[5 * SPPB];
    __shared__ int lch[NCB];                   // block-local coarse hist (block = one level)
    const int tid = threadIdx.x;
    const int base = blockIdx.x * SPPB;
    for (int i = tid; i < NCB; i += 256) lch[i] = 0;
    for (int it = tid; it < 5 * SPPB; it += 256) {
        int c = it / SPPB, pt = it - c * SPPB;
        int g = base + pt, lv, p, HW;
        locate(g, lv, p, HW);
        const float* cls = (lv == 0) ? cls0 : ((lv == 1) ? cls1 : cls2);
        const float* bp = cls + (size_t)c * 16 * HW + p;
        float x[16];
#pragma unroll
        for (int cc = 0; cc < 16; cc++) x[cc] = bp[(size_t)cc * HW];   // independent loads (MLP)
        float m = -INFINITY, v = -INFINITY; int idx = 0;
#pragma unroll
        for (int cc = 0; cc < 16; cc++)
            if (x[cc] > m) { v = m; m = x[cc]; idx = c * 16 + cc; }    // first-occurrence
        pm[it] = m; pv[it] = v; pidx[it] = idx;
    }
    __syncthreads();
    if (tid < SPPB) {
        int g = base + tid, lv, p, HW;
        locate(g, lv, p, HW);
        const float* ctn = (lv == 0) ? ctn0 : ((lv == 1) ? ctn1 : ctn2);
        float m = -INFINITY, v = -INFINITY; int idx = 0;
#pragma unroll
        for (int k = 0; k < 5; k++) {
            float bm = pm[k * SPPB + tid];
            float bv = pv[k * SPPB + tid];
            int bidx = pidx[k * SPPB + tid];
            if (bm > m) { v = fmaxf(m, bv); m = bm; idx = bidx; }
        }
        // joint = sqrt(sig(cls)*sig(ctn)) weakly monotone in cls -> max joint = joint(m)
        float sc = sig_f32_stepwise(ctn[p]);
        float sM = sig_f32_stepwise(m);
        float jm = __fsqrt_rn(sM * sc);
        float sV = sig_f32_stepwise(v);
        float jv = __fsqrt_rn(sV * sc);
        if (jv == jm) {                        // earlier-index label tie possible
            int f = atomicAdd(&cnt[13], 1);
            if (f < FCAP) flags[f] = (unsigned)g;
        }
        unsigned int bits = __float_as_uint(jm);
        keys[g] = ((unsigned long long)bits << 32) | (0xFFFFFFFFu - (unsigned)g);
        labels[g] = idx;
        atomicAdd(&hist[lv * NB + (int)(bits >> 12)], 1);     // fine (high-entropy: low contention)
        atomicAdd(&lch[(int)(bits >> 20)], 1);                // coarse -> LDS (contention-free-ish)
    }
    __syncthreads();
    // flush aggregated coarse bins: <=1 global atomic per bin per block
    int lv0, p0, HW0; locate(base, lv0, p0, HW0);             // whole block is in level lv0
    for (int i = tid; i < NCB; i += 256) {
        int v = lch[i];
        if (v) atomicAdd(&chist[lv0 * NCB + i], v);
    }
}

// ---------------- kernel 2: thresh via coarse+fine hist (blocks 0-2) + cleanup (block 3) ----
__global__ __launch_bounds__(1024) void thresh_kernel(
        const float* __restrict__ cls0, const float* __restrict__ cls1,
        const float* __restrict__ cls2,
        const float* __restrict__ ctn0, const float* __restrict__ ctn1,
        const float* __restrict__ ctn2,
        const int* __restrict__ hist, const int* __restrict__ chist,
        int* __restrict__ cnt,
        const unsigned* __restrict__ flags, int* __restrict__ labels) {
    int bid = blockIdx.x, tid = threadIdx.x;
    if (bid < 3) {
        int lv = bid;
        const int* h = hist + lv * NB;
        __shared__ int part[1024];
        __shared__ int s_chunk, s_above;
        __shared__ int bins[257];
        part[tid] = chist[lv * NCB + tid];     // coarse bin count == sum of its 256 fine bins
        __syncthreads();
        for (int off = 1; off < 1024; off <<= 1) {
            int v = part[tid] + ((tid + off < 1024) ? part[tid + off] : 0);
            __syncthreads(); part[tid] = v; __syncthreads();
        }
        int nxt = (tid < 1023) ? part[tid + 1] : 0;
        if (part[tid] >= K_TOP && nxt < K_TOP) { s_chunk = tid; s_above = nxt; }
        __syncthreads();
        int chunk = s_chunk, above = s_above;
        if (tid < 256) bins[tid] = h[chunk * 256 + tid];
        __syncthreads();
        for (int off = 1; off < 256; off <<= 1) {
            int v = 0;
            if (tid < 256) v = bins[tid] + ((tid + off < 256) ? bins[tid + off] : 0);
            __syncthreads(); if (tid < 256) bins[tid] = v; __syncthreads();
        }
        if (tid < 256) {
            int ge    = above + bins[tid];
            int genxt = above + ((tid < 255) ? bins[tid + 1] : 0);
            if (ge >= K_TOP && genxt < K_TOP) {
                cnt[6 + lv] = chunk * 256 + tid;  // cutoff bin B (fine)
                cnt[9 + lv] = K_TOP - genxt;      // R needed from bin B
            }
        }
    } else {
        // cleanup: one wave per flagged point, shuffle argmax-reduce (first occurrence = min idx)
        int nf = cnt[13]; if (nf > FCAP) nf = FCAP;
        int wave = tid >> 6, lane = tid & 63;
        for (int f = wave; f < nf; f += 16) {
            int g = (int)flags[f], lv, p, HW;
            locate(g, lv, p, HW);
            const float* cls = (lv == 0) ? cls0 : ((lv == 1) ? cls1 : cls2);
            const float* ctn = (lv == 0) ? ctn0 : ((lv == 1) ? ctn1 : ctn2);
            float sc = sig_f32_stepwise(ctn[p]);
            float bestv = -1.0f; int besti = 127;
            {
                float s = sig_f32_stepwise(cls[(size_t)lane * HW + p]);
                float sj = __fsqrt_rn(s * sc);
                bestv = sj; besti = lane;
            }
            if (lane < 16) {
                int c2 = lane + 64;
                float s = sig_f32_stepwise(cls[(size_t)c2 * HW + p]);
                float sj = __fsqrt_rn(s * sc);
                if (sj > bestv) { bestv = sj; besti = c2; }   // tie keeps smaller idx
            }
            for (int off = 32; off; off >>= 1) {
                float ov = __shfl_xor(bestv, off, 64);
                int   oi = __shfl_xor(besti, off, 64);
                if (ov > bestv || (ov == bestv && oi < besti)) { bestv = ov; besti = oi; }
            }
            if (lane == 0) labels[g] = besti;
        }
    }
}

// ---------------- kernel 3: compact sure / candidate keys ----------------
__global__ void compact_kernel(const unsigned long long* __restrict__ keys,
                               int* __restrict__ cnt,
                               unsigned long long* __restrict__ sure,
                               unsigned long long* __restrict__ cand) {
    int g = blockIdx.x * blockDim.x + threadIdx.x;
    if (g >= NPTS) return;
    int lv = (g < 65536) ? 0 : (g < 81920 ? 1 : 2);
    unsigned long long key = keys[g];
    int bin = (int)(key >> 44);      // == f32 bits >> 12
    int B = cnt[6 + lv];
    if (bin > B) {
        int i = atomicAdd(&cnt[0 + lv], 1);
        sure[lv * 1024 + i] = key;
    } else if (bin == B) {
        int i = atomicAdd(&cnt[3 + lv], 1);
        if (i < CAND_CAP) cand[lv * CAND_CAP + i] = key;
    }
}

// ---------------- kernel 4: per-level candidate sort + fully-sorted level list ----------------
__global__ void select_kernel(const int* __restrict__ cnt,
                              const unsigned long long* __restrict__ sure,
                              unsigned long long* __restrict__ cand,
                              unsigned long long* __restrict__ surv) {
    int lv = blockIdx.x, tid = threadIdx.x;
    unsigned long long* c = cand + lv * CAND_CAP;
    int n = cnt[3 + lv]; if (n > CAND_CAP) n = CAND_CAP;
    int R = cnt[9 + lv];
    int Ca = K_TOP - R;
    int m = 1; while (m < n) m <<= 1;
    for (int t = n + tid; t < m; t += 1024) c[t] = 0ULL;
    __syncthreads();
    for (int k = 2; k <= m; k <<= 1)
        for (int j = k >> 1; j > 0; j >>= 1) {
            for (int t = tid; t < m; t += 1024) {
                int l = t ^ j;
                if (l > t) {
                    unsigned long long a = c[t], b = c[l];
                    if (((t & k) == 0) ? (a < b) : (a > b)) { c[t] = b; c[l] = a; }
                }
            }
            __syncthreads();
        }
    __shared__ unsigned long long s[1024];
    s[tid] = (tid < Ca) ? sure[lv * 1024 + tid]
                        : ((tid < K_TOP) ? c[tid - Ca] : 0ULL);
    __syncthreads();
    for (int k = 2; k <= 1024; k <<= 1)
        for (int j = k >> 1; j > 0; j >>= 1) {
            int l = tid ^ j;
            if (l > tid) {
                unsigned long long a = s[tid], b = s[l];
                if (((tid & k) == 0) ? (a < b) : (a > b)) { s[tid] = b; s[l] = a; }
            }
            __syncthreads();
        }
    if (tid < K_TOP) surv[lv * K_TOP + tid] = s[tid];    // sorted descending
}

// ---------------- kernel 5: 3-way merge by ranking + emit ----------------
__global__ __launch_bounds__(1024) void merge_emit_kernel(
        const unsigned long long* __restrict__ surv,
        const int* __restrict__ labels,
        const float* __restrict__ reg0, const float* __restrict__ reg1,
        const float* __restrict__ reg2,
        const float* __restrict__ scales,
        float* __restrict__ out) {
    __shared__ unsigned long long L[3][1024];
    __shared__ unsigned long long s[NOUT];
    int tid = threadIdx.x;
#pragma unroll
    for (int lv = 0; lv < 3; lv++)
        L[lv][tid] = (tid < K_TOP) ? surv[lv * K_TOP + tid] : 0ULL;
    __syncthreads();
    for (int e = tid; e < NOUT; e += 1024) {
        int a = e / K_TOP, i = e - a * K_TOP;
        unsigned long long key = L[a][i];
        int rank = i;
#pragma unroll
        for (int b = 0; b < 3; b++) {
            if (b == a) continue;
            int lo = 0, hi = K_TOP;
            while (lo < hi) {
                int mid = (lo + hi) >> 1;
                if (L[b][mid] > key) lo = mid + 1; else hi = mid;
            }
            rank += lo;
        }
        s[rank] = key;    // keys unique -> bijective
    }
    __syncthreads();
    for (int r = tid; r < NOUT; r += 1024) {
        unsigned long long key = s[r];
        unsigned int bits = (unsigned)(key >> 32);
        float score = __uint_as_float(bits);
        unsigned int g = 0xFFFFFFFFu - (unsigned)(key & 0xFFFFFFFFULL);
        int lv, p;
        if (g < 65536u)      { lv = 0; p = (int)g; }
        else if (g < 81920u) { lv = 1; p = (int)g - 65536; }
        else                 { lv = 2; p = (int)g - 81920; }
        const float* rp = (lv == 0) ? reg0 : ((lv == 1) ? reg1 : reg2);
        int HW = (lv == 0) ? 65536 : ((lv == 1) ? 16384 : 4096);
        int W = 256 >> lv;
        float strideF = (float)(8 << lv);
        float scale = scales[lv];
        int x = p & (W - 1);
        int y = p >> (8 - lv);
        float r0 = fmaxf(0.0f, rp[0 * HW + p] * scale) * strideF;
        float r1 = fmaxf(0.0f, rp[1 * HW + p] * scale) * strideF;
        float r2 = fmaxf(0.0f, rp[2 * HW + p] * scale) * strideF;
        float r3 = fmaxf(0.0f, rp[3 * HW + p] * scale) * strideF;
        float ax = ((float)x + 0.5f) * strideF;
        float ay = ((float)y + 0.5f) * strideF;
        out[r * 4 + 0] = ax - r0;
        out[r * 4 + 1] = ay - r1;
        out[r * 4 + 2] = ax + r2;
        out[r * 4 + 3] = ay + r3;
        out[12000 + r] = score;
        out[15000 + r] = (float)labels[g];
    }
}

// ---------------- kernel 6: tiled sparse edge extraction (SoA LDS) ----------------
__global__ __launch_bounds__(256) void edge_kernel(const float* __restrict__ out,
                                                   unsigned* __restrict__ edges_g,
                                                   int* __restrict__ cnt) {
    __shared__ float x1[128], y1[128], x2[128], y2[128];
    int t = blockIdx.x, tid = threadIdx.x;
    int ta = 0, rem = t;
    while (rem >= NTILE - ta) { rem -= NTILE - ta; ta++; }
    int tb = ta + rem;                         // ta <= tb
    if (tid < 64) {
        int gi = ta * 64 + tid;
        if (gi < NOUT) {
            float4 b = ((const float4*)out)[gi];
            x1[tid] = b.x; y1[tid] = b.y; x2[tid] = b.z; y2[tid] = b.w;
        }
    } else if (tid < 128) {
        int gj = tb * 64 + (tid - 64);
        if (gj < NOUT) {
            float4 b = ((const float4*)out)[gj];
            x1[tid] = b.x; y1[tid] = b.y; x2[tid] = b.z; y2[tid] = b.w;
        }
    }
    __syncthreads();
#pragma unroll
    for (int q = 0; q < 16; q++) {
        int idx = q * 256 + tid;
        int ii = idx >> 6, jj = idx & 63;
        int i = ta * 64 + ii, j = tb * 64 + jj;
        if (i < j && j < NOUT) {
            float ai = (x2[ii] - x1[ii]) * (y2[ii] - y1[ii]);
            float aj = (x2[64 + jj] - x1[64 + jj]) * (y2[64 + jj] - y1[64 + jj]);
            float xx1 = fmaxf(x1[ii], x1[64 + jj]), yy1 = fmaxf(y1[ii], y1[64 + jj]);
            float xx2 = fminf(x2[ii], x2[64 + jj]), yy2 = fminf(y2[ii], y2[64 + jj]);
            float ww = fmaxf(1e-10f, xx2 - xx1);
            float hh = fmaxf(1e-10f, yy2 - yy1);
            float inter = ww * hh;
            float iou = inter / (((ai + aj) - inter) + 1e-14f);
            if ((double)iou > 0.6) {
                int e = atomicAdd(&cnt[12], 1);
                if (e < ECAP) edges_g[e] = ((unsigned)i << 12) | (unsigned)j;
            }
        }
    }
}

// ---------------- kernel 7: sparse sequential NMS (single block) ----------------
__global__ __launch_bounds__(1024) void nms_sparse_kernel(
        const unsigned* __restrict__ edges_g,
        const int* __restrict__ cnt,
        const float* __restrict__ scores_s,
        float* __restrict__ keep_out) {
    __shared__ unsigned ed[ECAP];
    __shared__ unsigned long long supLds[NWORDS];
    int tid = threadIdx.x;
    int E = cnt[12]; if (E > ECAP) E = ECAP;
    int m = 1; while (m < E) m <<= 1;
    for (int t = tid; t < m; t += 1024) ed[t] = (t < E) ? edges_g[t] : 0xFFFFFFFFu;
    __syncthreads();
    for (int k = 2; k <= m; k <<= 1)
        for (int j = k >> 1; j > 0; j >>= 1) {
            for (int t = tid; t < m; t += 1024) {
                int l = t ^ j;
                if (l > t) {
                    unsigned a = ed[t], b = ed[l];
                    if (((t & k) == 0) ? (a > b) : (a < b)) { ed[t] = b; ed[l] = a; }
                }
            }
            __syncthreads();
        }
    if (tid < 64) {
        int lane = tid;
        unsigned long long supW = 0ULL;
        int ep = 0;
        for (int c = 0; c < NWORDS; c++) {
            unsigned long long cw = __shfl(supW, c, 64);   // complete: sources < c*64 final
            int hi = (c + 1) * 64;
            while (ep < E) {
                unsigned k = ed[ep];
                int i = (int)(k >> 12);
                if (i >= hi) break;
                int j = (int)(k & 4095);
                if (!((cw >> (i & 63)) & 1ULL)) {          // source kept -> suppress target
                    if ((j >> 6) == c) cw |= 1ULL << (j & 63);
                    else if (lane == (j >> 6)) supW |= 1ULL << (j & 63);
                }
                ep++;
            }
            if (lane == c) supW = cw;
        }
        if (lane < NWORDS) supLds[lane] = supW;
    }
    __syncthreads();
    for (int j = tid; j < NOUT; j += 1024) {
        bool s = (supLds[j >> 6] >> (j & 63)) & 1ULL;
        float scv = scores_s[j];
        keep_out[j] = (!s && ((double)scv > 0.05)) ? 1.0f : 0.0f;
    }
}

extern "C" void kernel_launch(void* const* d_in, const int* in_sizes, int n_in,
                              void* d_out, int out_size, void* d_ws, size_t ws_size,
                              hipStream_t stream) {
    const float* cls0 = (const float*)d_in[0];
    const float* reg0 = (const float*)d_in[1];
    const float* ctn0 = (const float*)d_in[2];
    const float* cls1 = (const float*)d_in[3];
    const float* reg1 = (const float*)d_in[4];
    const float* ctn1 = (const float*)d_in[5];
    const float* cls2 = (const float*)d_in[6];
    const float* reg2 = (const float*)d_in[7];
    const float* ctn2 = (const float*)d_in[8];
    const float* scales = (const float*)d_in[9];

    char* ws = (char*)d_ws;
    int* hist = (int*)(ws + HIST_OFF);
    int* chist = (int*)(ws + CH_OFF);
    int* cnt  = (int*)(ws + CNT_OFF);
    unsigned long long* keys = (unsigned long long*)(ws + KEYS_OFF);
    int* labels = (int*)(ws + LAB_OFF);
    unsigned long long* sure = (unsigned long long*)(ws + SURE_OFF);
    unsigned long long* cand = (unsigned long long*)(ws + CAND_OFF);
    unsigned long long* surv = (unsigned long long*)(ws + SURV_OFF);
    unsigned* edges = (unsigned*)(ws + EDGE_OFF);
    unsigned* flags = (unsigned*)(ws + FLAG_OFF);
    float* out = (float*)d_out;

    hipMemsetAsync(ws, 0, MEMSET_BYTES, stream);

    score_kernel<<<NPTS / SPPB, 256, 0, stream>>>(cls0, cls1, cls2, ctn0, ctn1, ctn2,
                                                  keys, labels, hist, chist, cnt, flags);
    thresh_kernel<<<4, 1024, 0, stream>>>(cls0, cls1, cls2, ctn0, ctn1, ctn2,
                                          hist, chist, cnt, flags, labels);
    compact_kernel<<<(NPTS + 255) / 256, 256, 0, stream>>>(keys, cnt, sure, cand);
    select_kernel<<<3, 1024, 0, stream>>>(cnt, sure, cand, surv);
    merge_emit_kernel<<<1, 1024, 0, stream>>>(surv, labels, reg0, reg1, reg2, scales, out);
    edge_kernel<<<NTILE * (NTILE + 1) / 2, 256, 0, stream>>>(out, edges, cnt);
    nms_sparse_kernel<<<1, 1024, 0, stream>>>(edges, cnt, out + 12000, out + 18000);
}